// Round 3
// baseline (5000.779 us; speedup 1.0000x reference)
//
#include <hip/hip_runtime.h>
#include <math.h>

// Problem constants: D=3, H=64, WIN=8, OUT=32, B=128, T=129
#define BB 128
#define TT 129
#define NSTEP 128
#define NW 16
#define WINW 8
#define OUTD 32

typedef _Float16 h2_t __attribute__((ext_vector_type(2)));

__device__ __forceinline__ float fast_rcp(float v){ return __builtin_amdgcn_rcpf(v); }
__device__ __forceinline__ float softplus_f(float v){ return fmaxf(v,0.f)+__logf(1.f+__expf(-fabsf(v))); }
__device__ __forceinline__ float sigmoid_f(float v){ return fast_rcp(1.f+__expf(-v)); }
__device__ __forceinline__ float tanh_f(float v){
    float ax=fminf(fabsf(v),15.f); float e=__expf(2.f*ax);
    float r=1.f-2.f*fast_rcp(e+1.f); return copysignf(r,v);
}
__device__ __forceinline__ float pack2(float a,float b){
    h2_t h; h.x=(_Float16)a; h.y=(_Float16)b; return __builtin_bit_cast(float,h);
}
__device__ __forceinline__ float dot2c(float wc,float ac,float acc){
    return __builtin_amdgcn_fdot2(__builtin_bit_cast(h2_t,wc),__builtin_bit_cast(h2_t,ac),acc,false);
}
__device__ __forceinline__ float dot2q(float4 wq,float4 aq,float acc){
    acc=dot2c(wq.x,aq.x,acc); acc=dot2c(wq.y,aq.y,acc);
    acc=dot2c(wq.z,aq.z,acc); acc=dot2c(wq.w,aq.w,acc); return acc;
}
#define DOT4(acc,Wv,Av) acc += (Wv).x*(Av).x + (Wv).y*(Av).y + (Wv).z*(Av).z + (Wv).w*(Av).w
#define PIN4(q) asm volatile("" : "+v"((q).x), "+v"((q).y), "+v"((q).z), "+v"((q).w))

// K=64 dot: 8 float4 of packed halves, 2 accumulator chains
__device__ __forceinline__ float dotN8(const float4* w, const float4* a){
    float p=0.f,q=0.f;
    #pragma unroll
    for (int k=0;k<8;k+=2){ p=dot2q(w[k],a[k],p); q=dot2q(w[k+1],a[k+1],q); }
    return p+q;
}
// K=128 dot: 16 float4
__device__ __forceinline__ float dotN16(const float4* w, const float4* a){
    float p=0.f,q=0.f;
    #pragma unroll
    for (int k=0;k<16;k+=2){ p=dot2q(w[k],a[k],p); q=dot2q(w[k+1],a[k+1],q); }
    return p+q;
}

// One wave per batch. Lane l owns rows {l, 64+l, 128+l} of every layer.
__global__ __launch_bounds__(64, 1)
void ncde_solve(const float* __restrict__ ts, const float* __restrict__ x,
                const float* __restrict__ W0, const float* __restrict__ b0,
                const float* __restrict__ W1, const float* __restrict__ b1,
                const float* __restrict__ W2, const float* __restrict__ b2,
                const float* __restrict__ V0, const float* __restrict__ c0,
                const float* __restrict__ V1, const float* __restrict__ c1,
                const float* __restrict__ V2, const float* __restrict__ c2,
                const float* __restrict__ R, const float* __restrict__ rb,
                float* __restrict__ out)
{
    const int b = blockIdx.x;
    const int l = threadIdx.x;   // lane 0..63; single wave => NO barriers anywhere

    // ---- LDS ----
    // V2 packed fp16: 192 rows x 64 words, stride 66 words (stride%32==2 -> 2-way conflicts only, free; 8B aligned for b64)
    __shared__ __align__(16) float V2L[192*66];
    // R packed fp16: 32 rows x 32 words, stride 34
    __shared__ __align__(16) float RL[32*34];
    __shared__ __align__(16) float yH[32],  y2H[32];     // 64 halves
    __shared__ __align__(16) float a0H[64], a1H[64];     // 128 halves
    __shared__ __align__(16) float mH[96];               // 192 halves
    __shared__ __align__(16) float u0H[192], u1H[192];   // 3 x 128 halves
    __shared__ __align__(16) float hA[128], hB[128];     // fp32 h0 scratch
    __shared__ float slpL[NW*6];
    __shared__ float dtsL[NSTEP];

    // ---- fp16-packed weight registers: V0 rows {l,64+l} (8 f4 each), V1 rows {l,64+l} (16 f4 each) ----
    float4 v0r[2][8];
    float4 v1r[2][16];
    {
        #pragma unroll
        for (int r2=0;r2<2;r2++){
            const float4* p = (const float4*)(V0 + (l + 64*r2)*64);
            #pragma unroll
            for (int c=0;c<8;c++){
                float4 a=p[2*c], bq=p[2*c+1];
                float4 r; r.x=pack2(a.x,a.y); r.y=pack2(a.z,a.w); r.z=pack2(bq.x,bq.y); r.w=pack2(bq.z,bq.w);
                v0r[r2][c]=r;
            }
        }
        #pragma unroll
        for (int r2=0;r2<2;r2++){
            const float4* p = (const float4*)(V1 + (l + 64*r2)*128);
            #pragma unroll
            for (int c=0;c<16;c++){
                float4 a=p[2*c], bq=p[2*c+1];
                float4 r; r.x=pack2(a.x,a.y); r.y=pack2(a.z,a.w); r.z=pack2(bq.x,bq.y); r.w=pack2(bq.z,bq.w);
                v1r[r2][c]=r;
            }
        }
        #pragma unroll
        for (int r2=0;r2<2;r2++){ 
            #pragma unroll
            for (int c=0;c<8;c++) PIN4(v0r[r2][c]);
        }
        #pragma unroll
        for (int r2=0;r2<2;r2++){
            #pragma unroll
            for (int c=0;c<16;c++) PIN4(v1r[r2][c]);
        }
    }
    // V2 -> LDS (each lane stages its own 3 rows)
    #pragma unroll
    for (int r3=0;r3<3;r3++){
        const int row = l + 64*r3;
        const float4* p = (const float4*)(V2 + row*128);
        float* dst = V2L + row*66;
        #pragma unroll
        for (int c=0;c<32;c++){
            float4 a=p[c];
            float2 w2; w2.x=pack2(a.x,a.y); w2.y=pack2(a.z,a.w);
            *(float2*)(dst + 2*c) = w2;
        }
    }
    // R -> LDS (lanes 0..31)
    if (l < 32){
        const float4* p = (const float4*)(R + l*64);
        float* dst = RL + l*34;
        #pragma unroll
        for (int c=0;c<16;c++){
            float4 a=p[c];
            float2 w2; w2.x=pack2(a.x,a.y); w2.y=pack2(a.z,a.w);
            *(float2*)(dst + 2*c) = w2;
        }
    }

    const float c0A=c0[l], c0B=c0[64+l];
    const float c1A=c1[l], c1B=c1[64+l];
    const float c2A=c2[l], c2B=c2[64+l], c2C=c2[128+l];
    const float rbl = rb[l & 31];

    const float* tsb = ts + b*TT;
    for (int i=l; i<NSTEP; i+=64) dtsL[i] = tsb[i+1] - tsb[i];

    // ---- log-signature slopes (lanes 0..15) ----
    if (l < NW) {
        const int w = l;
        const float* xs = x + (size_t)(b*TT + w*WINW)*3;
        float x0c[3] = {xs[0], xs[1], xs[2]};
        float prev[3] = {x0c[0], x0c[1], x0c[2]};
        float am01=0.f, am02=0.f, am12=0.f, am10=0.f, am20=0.f, am21=0.f;
        #pragma unroll
        for (int k=0;k<WINW;k++) {
            float cur[3] = {xs[(k+1)*3+0], xs[(k+1)*3+1], xs[(k+1)*3+2]};
            float rel[3], dv[3];
            #pragma unroll
            for (int c=0;c<3;c++){ rel[c]=prev[c]-x0c[c]; dv[c]=cur[c]-prev[c]; }
            am01 += rel[0]*dv[1]; am10 += rel[1]*dv[0];
            am02 += rel[0]*dv[2]; am20 += rel[2]*dv[0];
            am12 += rel[1]*dv[2]; am21 += rel[2]*dv[1];
            prev[0]=cur[0]; prev[1]=cur[1]; prev[2]=cur[2];
        }
        const float invden = 1.f/(tsb[(w+1)*WINW] - tsb[w*WINW]);
        slpL[w*6+0] = (prev[0]-x0c[0])*invden;
        slpL[w*6+1] = (prev[1]-x0c[1])*invden;
        slpL[w*6+2] = (prev[2]-x0c[2])*invden;
        slpL[w*6+3] = 0.5f*(am01-am10)*invden;
        slpL[w*6+4] = 0.5f*(am02-am20)*invden;
        slpL[w*6+5] = 0.5f*(am12-am21)*invden;
    }

    // ---- h0 = init_mlp(x[b,0,:]) in fp32 (single wave, in-order LDS, no barriers) ----
    {
        const float* xb = x + (size_t)b*TT*3;
        const float xv0=xb[0], xv1=xb[1], xv2=xb[2];
        #pragma unroll
        for (int r2=0;r2<2;r2++){
            const int row = l + 64*r2;
            float acc = b0[row] + W0[row*3]*xv0 + W0[row*3+1]*xv1 + W0[row*3+2]*xv2;
            hA[row] = softplus_f(acc);
        }
        #pragma unroll
        for (int r2=0;r2<2;r2++){
            const int row = l + 64*r2;
            float acc = b1[row];
            const float4* wp = (const float4*)(W1 + row*128);
            #pragma unroll 8
            for (int k=0;k<32;k++){ float4 wv=wp[k]; float4 av=*(const float4*)&hA[4*k]; DOT4(acc,wv,av); }
            hB[row] = softplus_f(acc);
        }
    }
    float yreg;
    {
        float acc = b2[l];
        const float4* wp = (const float4*)(W2 + l*128);
        #pragma unroll 8
        for (int k=0;k<32;k++){ float4 wv=wp[k]; float4 av=*(const float4*)&hB[4*k]; DOT4(acc,wv,av); }
        yreg = acc;
        ((_Float16*)yH)[l] = (_Float16)yreg;
    }

    // ---- slopes regs (assigned per step, captured by Feval) ----
    float S0,S1,S2,S3,S4,S5;

    // V2 row dot: row from LDS (float2 stream), activation a = 16 f4 packed halves
    auto dotV2 = [&](int row, const float4* a) -> float {
        const float2* w2 = (const float2*)(V2L + row*66);
        float p=0.f,q=0.f;
        #pragma unroll
        for (int j=0;j<16;j+=2){
            float2 wa=w2[2*j], wb=w2[2*j+1], wc=w2[2*j+2], wd=w2[2*j+3];
            float4 A=a[j], Bq=a[j+1];
            p=dot2c(wa.x,A.x,p); p=dot2c(wa.y,A.y,p); p=dot2c(wb.x,A.z,p); p=dot2c(wb.y,A.w,p);
            q=dot2c(wc.x,Bq.x,q); q=dot2c(wc.y,Bq.y,q); q=dot2c(wd.x,Bq.z,q); q=dot2c(wd.y,Bq.w,q);
        }
        return p+q;
    };
    // V2 row read once, dotted against two tangent vectors (LDS broadcast reads in-loop)
    auto dotV2dual = [&](int row, const float* u1a, const float* u1b, float& ra, float& rbo){
        const float2* w2 = (const float2*)(V2L + row*66);
        const float4* A = (const float4*)u1a;
        const float4* Bv = (const float4*)u1b;
        float pa=0.f,qa=0.f,pb=0.f,qb=0.f;
        #pragma unroll
        for (int j=0;j<16;j+=2){
            float2 wa=w2[2*j], wb=w2[2*j+1], wc=w2[2*j+2], wd=w2[2*j+3];
            float4 Aa=A[j], Ab=A[j+1], Ba=Bv[j], Bb=Bv[j+1];
            pa=dot2c(wa.x,Aa.x,pa); pa=dot2c(wa.y,Aa.y,pa); pa=dot2c(wb.x,Aa.z,pa); pa=dot2c(wb.y,Aa.w,pa);
            qa=dot2c(wc.x,Ab.x,qa); qa=dot2c(wc.y,Ab.y,qa); qa=dot2c(wd.x,Ab.z,qa); qa=dot2c(wd.y,Ab.w,qa);
            pb=dot2c(wa.x,Ba.x,pb); pb=dot2c(wa.y,Ba.y,pb); pb=dot2c(wb.x,Ba.z,pb); pb=dot2c(wb.y,Ba.w,pb);
            qb=dot2c(wc.x,Bb.x,qb); qb=dot2c(wc.y,Bb.y,qb); qb=dot2c(wd.x,Bb.z,qb); qb=dot2c(wd.y,Bb.w,qb);
        }
        ra=pa+qa; rbo=pb+qb;
    };

    auto Feval = [&](const float* yBufH) -> float {
        // S1: z0 = V0@y + c0 (rows l, 64+l)
        float4 ya[8];
        {   const float4* s=(const float4*)yBufH;
            #pragma unroll
            for (int k=0;k<8;k++) ya[k]=s[k]; }
        float z0a = c0A + dotN8(v0r[0], ya);
        float z0b = c0B + dotN8(v0r[1], ya);
        float a0a=softplus_f(z0a), a0b=softplus_f(z0b);
        float sg0a=sigmoid_f(z0a), sg0b=sigmoid_f(z0b);
        ((_Float16*)a0H)[l]=(_Float16)a0a; ((_Float16*)a0H)[64+l]=(_Float16)a0b;
        // S2
        float4 aa[16];
        {   const float4* s=(const float4*)a0H;
            #pragma unroll
            for (int k=0;k<16;k++) aa[k]=s[k]; }
        float z1a = c1A + dotN16(v1r[0], aa);
        float z1b = c1B + dotN16(v1r[1], aa);
        float a1a=softplus_f(z1a), a1b=softplus_f(z1b);
        float sg1a=sigmoid_f(z1a), sg1b=sigmoid_f(z1b);
        ((_Float16*)a1H)[l]=(_Float16)a1a; ((_Float16*)a1H)[64+l]=(_Float16)a1b;
        // S3
        float4 ab[16];
        {   const float4* s=(const float4*)a1H;
            #pragma unroll
            for (int k=0;k<16;k++) ab[k]=s[k]; }
        float m0 = tanh_f(c2A + dotV2(l,      ab));
        float m1 = tanh_f(c2B + dotV2(64+l,   ab));
        float m2 = tanh_f(c2C + dotV2(128+l,  ab));
        float d0=1.f-m0*m0, d1=1.f-m1*m1, d2=1.f-m2*m2;
        ((_Float16*)mH)[l]=(_Float16)m0; ((_Float16*)mH)[64+l]=(_Float16)m1; ((_Float16*)mH)[128+l]=(_Float16)m2;
        // S4: u0[d] = sig0 * (V0 @ m[d])
        #pragma unroll
        for (int d=0;d<3;d++){
            float4 md[8];
            {   const float4* s=(const float4*)(mH + d*32);
                #pragma unroll
                for (int k=0;k<8;k++) md[k]=s[k]; }
            float ua = sg0a * dotN8(v0r[0], md);
            float ub = sg0b * dotN8(v0r[1], md);
            ((_Float16*)u0H)[d*128 + l]      = (_Float16)ua;
            ((_Float16*)u0H)[d*128 + 64 + l] = (_Float16)ub;
        }
        // S5: u1[d] = sig1 * (V1 @ u0[d])
        #pragma unroll
        for (int d=0;d<3;d++){
            float4 ud[16];
            {   const float4* s=(const float4*)(u0H + d*64);
                #pragma unroll
                for (int k=0;k<16;k++) ud[k]=s[k]; }
            float ua = sg1a * dotN16(v1r[0], ud);
            float ub = sg1b * dotN16(v1r[1], ud);
            ((_Float16*)u1H)[d*128 + l]      = (_Float16)ua;
            ((_Float16*)u1H)[d*128 + 64 + l] = (_Float16)ub;
        }
        // S6+S7 fused: all six Jf values for output h=l are lane-local.
        // row l (block0) needs tangents {1,2}; row 64+l (block1) {0,2}; row 128+l (block2) {0,1}
        float J1h,J2h,J0h64,J2h64,J0h128,J1h128;
        dotV2dual(l,       u1H + 1*64, u1H + 2*64, J1h,    J2h);
        dotV2dual(64+l,    u1H + 0*64, u1H + 2*64, J0h64,  J2h64);
        dotV2dual(128+l,   u1H + 0*64, u1H + 1*64, J0h128, J1h128);
        J1h*=d0; J2h*=d0; J0h64*=d1; J2h64*=d1; J0h128*=d2; J1h128*=d2;
        return m0*S0 + m1*S1 + m2*S2
             + S3*(J0h64 - J1h) + S4*(J0h128 - J2h) + S5*(J1h128 - J2h64);
    };

    auto proj = [&](int stp){
        float4 yv[8];
        {   const float4* s=(const float4*)yH;
            #pragma unroll
            for (int k=0;k<8;k++) yv[k]=s[k]; }
        const float2* w2 = (const float2*)(RL + (l&31)*34);
        float p=0.f,q=0.f;
        #pragma unroll
        for (int j=0;j<8;j+=2){
            float2 wa=w2[2*j], wb=w2[2*j+1], wc=w2[2*j+2], wd=w2[2*j+3];
            float4 A=yv[j], Bq=yv[j+1];
            p=dot2c(wa.x,A.x,p); p=dot2c(wa.y,A.y,p); p=dot2c(wb.x,A.z,p); p=dot2c(wb.y,A.w,p);
            q=dot2c(wc.x,Bq.x,q); q=dot2c(wc.y,Bq.y,q); q=dot2c(wd.x,Bq.z,q); q=dot2c(wd.y,Bq.w,q);
        }
        if (l < 32) out[(size_t)(b*TT + stp)*OUTD + l] = tanh_f(p+q+rbl);
    };

    // ---- Heun scan ----
    for (int step=0; step<NSTEP; ++step){
        proj(step);
        const int w = step >> 3;
        S0=slpL[w*6+0]; S1=slpL[w*6+1]; S2=slpL[w*6+2];
        S3=slpL[w*6+3]; S4=slpL[w*6+4]; S5=slpL[w*6+5];
        const float dtc = dtsL[step];
        float k1 = Feval(yH);
        float y2 = yreg + dtc*k1;
        ((_Float16*)y2H)[l] = (_Float16)y2;
        float k2 = Feval(y2H);
        yreg = yreg + 0.5f*dtc*(k1+k2);
        ((_Float16*)yH)[l] = (_Float16)yreg;
    }
    proj(NSTEP);
}

extern "C" void kernel_launch(void* const* d_in, const int* in_sizes, int n_in,
                              void* d_out, int out_size, void* d_ws, size_t ws_size,
                              hipStream_t stream) {
    const float* ts = (const float*)d_in[0];
    const float* x  = (const float*)d_in[1];
    const float* W0 = (const float*)d_in[2];
    const float* b0 = (const float*)d_in[3];
    const float* W1 = (const float*)d_in[4];
    const float* b1 = (const float*)d_in[5];
    const float* W2 = (const float*)d_in[6];
    const float* b2 = (const float*)d_in[7];
    const float* V0 = (const float*)d_in[8];
    const float* c0 = (const float*)d_in[9];
    const float* V1 = (const float*)d_in[10];
    const float* c1 = (const float*)d_in[11];
    const float* V2 = (const float*)d_in[12];
    const float* c2 = (const float*)d_in[13];
    const float* R  = (const float*)d_in[14];
    const float* rb = (const float*)d_in[15];
    float* out = (float*)d_out;

    ncde_solve<<<dim3(BB), dim3(64), 0, stream>>>(
        ts, x, W0, b0, W1, b1, W2, b2, V0, c0, V1, c1, V2, c2, R, rb, out);
}